// Round 8
// baseline (422.447 us; speedup 1.0000x reference)
//
#include <hip/hip_runtime.h>
#include <math.h>

#define D_MODEL 1024
#define N_RES   2048
#define BATCH   32
constexpr float INV_2PI = 0.15915494309189535f;

// ws layout (float units). All coefficient matrices pre-transposed so the
// phase kernels do lane-coalesced loads along their serial-K loops.
#define WS_IPWT 0                          // ipwT [2048 k][1024 d]
#define WS_AT   (WS_IPWT + 2048 * 1024)    // at   [1024 d][2048 n] = INV_2PI/(1+|W|)
#define WS_CT   (WS_AT   + 1024 * 2048)    // ct   [1024 d][2048 n] = B*INV_2PI
#define WS_ORWT (WS_CT   + 1024 * 2048)    // orwT [2048 n][1024 d]
#define WS_OIWT (WS_ORWT + 2048 * 1024)    // oiwT [2048 n][1024 d]
#define WS_PA   (WS_OIWT + 2048 * 1024)    // pa   [8 q][32 b][1024 d]
#define WS_CS   (WS_PA   + 8 * 32 * 1024)  // cs   [32][2048]
#define WS_SS   (WS_CS   + 32 * 2048)      // ss   [32][2048]

__device__ __forceinline__ float silu(float v) { return v / (1.f + __expf(-v)); }

// ---------------------------------------------------------------------------
// kT: tiled transposes of all 5 coefficient matrices (+ W/B transforms).
// 5 x 512 tiles of 64x64 via LDS. Pure streaming (80 MB rw) — control
// experiment: fills stream at 6.4 TB/s, so this should run ~16 us.
// ---------------------------------------------------------------------------
__global__ __launch_bounds__(256) void kT(const float* __restrict__ ipw,
                                          const float* __restrict__ W,
                                          const float* __restrict__ Bm,
                                          const float* __restrict__ orw,
                                          const float* __restrict__ oiw,
                                          float* __restrict__ ws) {
  __shared__ float tile[64][65];
  const int m = blockIdx.x >> 9;    // matrix id
  const int t = blockIdx.x & 511;   // tile id
  const float* src;
  float* dst;
  int R, C, mode;
  if (m == 0)      { src = ipw; dst = ws + WS_IPWT; R = 1024; C = 2048; mode = 0; }
  else if (m == 1) { src = W;   dst = ws + WS_AT;   R = 2048; C = 1024; mode = 1; }
  else if (m == 2) { src = Bm;  dst = ws + WS_CT;   R = 2048; C = 1024; mode = 2; }
  else if (m == 3) { src = orw; dst = ws + WS_ORWT; R = 1024; C = 2048; mode = 0; }
  else             { src = oiw; dst = ws + WS_OIWT; R = 1024; C = 2048; mode = 0; }
  const int tpr = C >> 6;                       // tiles per src row-band
  const int tr = (t / tpr) << 6, tc = (t % tpr) << 6;
  const int r4 = threadIdx.x >> 6, cc = threadIdx.x & 63;

#pragma unroll
  for (int rr = 0; rr < 16; ++rr) {
    const int r = rr * 4 + r4;
    float v = src[(size_t)(tr + r) * C + tc + cc];
    if (mode == 1)      v = INV_2PI / (1.f + fabsf(v));
    else if (mode == 2) v = v * INV_2PI;
    tile[r][cc] = v;
  }
  __syncthreads();
#pragma unroll
  for (int rr = 0; rr < 16; ++rr) {
    const int r = rr * 4 + r4;
    dst[(size_t)(tc + r) * R + tr + cc] = tile[cc][r];
  }
}

// ---------------------------------------------------------------------------
// kA: input-GEMM partials. 256 blocks = (b 32) x (kchunk 8 of 256 k).
// Thread owns a float4 of d (lane-coalesced ipwT row loads); x[b][k] is a
// wave-uniform broadcast load. Serial K, NO cross-lane reduction.
// ---------------------------------------------------------------------------
__global__ __launch_bounds__(256) void kA(const float* __restrict__ xr,
                                          const float* __restrict__ xi,
                                          float* __restrict__ ws) {
  const int b = blockIdx.x >> 3, q = blockIdx.x & 7;
  const int tid = threadIdx.x;
  const float4* ipwT4 = (const float4*)(ws + WS_IPWT);  // 256 f4 per k-row
  const float4* xrow4 = (const float4*)((q < 4 ? xr + b * 1024 + q * 256
                                                : xi + b * 1024 + (q - 4) * 256));
  const int k0 = q * 256;

  float4 acc = {0.f, 0.f, 0.f, 0.f};
#pragma unroll 1
  for (int k4 = 0; k4 < 64; ++k4) {
    float4 xq = xrow4[k4];  // uniform broadcast (4 k's worth)
    float4 w0 = ipwT4[(size_t)(k0 + k4 * 4 + 0) * 256 + tid];
    float4 w1 = ipwT4[(size_t)(k0 + k4 * 4 + 1) * 256 + tid];
    float4 w2 = ipwT4[(size_t)(k0 + k4 * 4 + 2) * 256 + tid];
    float4 w3 = ipwT4[(size_t)(k0 + k4 * 4 + 3) * 256 + tid];
    acc.x += xq.x * w0.x + xq.y * w1.x + xq.z * w2.x + xq.w * w3.x;
    acc.y += xq.x * w0.y + xq.y * w1.y + xq.z * w2.y + xq.w * w3.y;
    acc.z += xq.x * w0.z + xq.y * w1.z + xq.z * w2.z + xq.w * w3.z;
    acc.w += xq.x * w0.w + xq.y * w1.w + xq.z * w2.w + xq.w * w3.w;
  }
  ((float4*)(ws + WS_PA))[(q * 32 + b) * 256 + tid] = acc;
}

// ---------------------------------------------------------------------------
// kB: sin/cos sums. 256 blocks = (b 32) x (ngroup 8 of 256 n). Thread owns
// ONE n (coalesced at/ct loads + coalesced cs/ss store); serial d with xc
// broadcast from LDS. Prologue folds the kA partial-combine + bias.
// NO cross-lane reduction anywhere.
// ---------------------------------------------------------------------------
__global__ __launch_bounds__(256) void kB(const float* __restrict__ t,
                                          const float* __restrict__ bias,
                                          float* __restrict__ ws) {
  __shared__ float xcl[D_MODEL];
  const int b = blockIdx.x >> 3, ng = blockIdx.x & 7;
  const int tid = threadIdx.x;
  const int n = ng * 256 + tid;

  {  // xc row b = sum_q pa[q][b][:] + bias
    const float4* pa4 = (const float4*)(ws + WS_PA);
    float4 s = ((const float4*)bias)[tid];
#pragma unroll
    for (int q = 0; q < 8; ++q) {
      float4 p = pa4[(q * 32 + b) * 256 + tid];
      s.x += p.x; s.y += p.y; s.z += p.z; s.w += p.w;
    }
    ((float4*)xcl)[tid] = s;
  }
  __syncthreads();

  const float t2 = t[b] * INV_2PI;
  const float* at = ws + WS_AT;
  const float* ct = ws + WS_CT;
  float sa0 = 0.f, sa1 = 0.f, ca0 = 0.f, ca1 = 0.f;
#pragma unroll 1
  for (int d4 = 0; d4 < 256; ++d4) {
    float4 x4 = ((const float4*)xcl)[d4];  // LDS broadcast
    const int r = d4 * 4;
    float a0 = at[(r + 0) * 2048 + n];
    float a1 = at[(r + 1) * 2048 + n];
    float a2 = at[(r + 2) * 2048 + n];
    float a3 = at[(r + 3) * 2048 + n];
    float f0 = ct[(r + 0) * 2048 + n];
    float f1 = ct[(r + 1) * 2048 + n];
    float f2 = ct[(r + 2) * 2048 + n];
    float f3 = ct[(r + 3) * 2048 + n];
    float th0 = __builtin_amdgcn_fractf(fmaf(x4.x, a0, f0) + t2);
    float th1 = __builtin_amdgcn_fractf(fmaf(x4.y, a1, f1) + t2);
    float th2 = __builtin_amdgcn_fractf(fmaf(x4.z, a2, f2) + t2);
    float th3 = __builtin_amdgcn_fractf(fmaf(x4.w, a3, f3) + t2);
    sa0 += __builtin_amdgcn_sinf(th0);
    ca0 += __builtin_amdgcn_cosf(th0);
    sa1 += __builtin_amdgcn_sinf(th1);
    ca1 += __builtin_amdgcn_cosf(th1);
    sa0 += __builtin_amdgcn_sinf(th2);
    ca0 += __builtin_amdgcn_cosf(th2);
    sa1 += __builtin_amdgcn_sinf(th3);
    ca1 += __builtin_amdgcn_cosf(th3);
  }
  ws[WS_CS + b * N_RES + n] = ca0 + ca1;
  ws[WS_SS + b * N_RES + n] = sa0 + sa1;
}

// ---------------------------------------------------------------------------
// kC: output GEMM + silu. 256 blocks = (comp 2) x (b 32) x (dquarter 4).
// Thread owns ONE d (coalesced wmT loads + coalesced out store); serial n
// with src row broadcast from LDS. NO cross-lane reduction.
// ---------------------------------------------------------------------------
__global__ __launch_bounds__(256) void kC(float* __restrict__ out,
                                          float* __restrict__ ws) {
  __shared__ float srcl[N_RES];
  const int comp = blockIdx.x >> 7;
  const int b    = (blockIdx.x >> 2) & 31;
  const int dq   = blockIdx.x & 3;
  const int tid  = threadIdx.x;
  const int d    = dq * 256 + tid;
  const float* srcp = ws + (comp ? WS_SS : WS_CS) + b * N_RES;
  const float* wmT  = ws + (comp ? WS_OIWT : WS_ORWT);  // [2048 n][1024 d]

  ((float4*)srcl)[tid]       = ((const float4*)srcp)[tid];
  ((float4*)srcl)[tid + 256] = ((const float4*)srcp)[tid + 256];
  __syncthreads();

  float acc = 0.f;
#pragma unroll 1
  for (int n4 = 0; n4 < 512; ++n4) {
    float4 s4 = ((const float4*)srcl)[n4];  // LDS broadcast
    const int r = n4 * 4;
    float w0 = wmT[(r + 0) * 1024 + d];
    float w1 = wmT[(r + 1) * 1024 + d];
    float w2 = wmT[(r + 2) * 1024 + d];
    float w3 = wmT[(r + 3) * 1024 + d];
    acc += s4.x * w0 + s4.y * w1 + s4.z * w2 + s4.w * w3;
  }
  out[comp * (BATCH * D_MODEL) + b * D_MODEL + d] = silu(acc);
}

extern "C" void kernel_launch(void* const* d_in, const int* in_sizes, int n_in,
                              void* d_out, int out_size, void* d_ws, size_t ws_size,
                              hipStream_t stream) {
  const float* xr   = (const float*)d_in[0];
  const float* xi   = (const float*)d_in[1];
  const float* t    = (const float*)d_in[2];
  const float* ipw  = (const float*)d_in[3];
  const float* bias = (const float*)d_in[4];
  const float* W    = (const float*)d_in[5];
  const float* Bm   = (const float*)d_in[6];
  const float* orw  = (const float*)d_in[7];
  const float* oiw  = (const float*)d_in[8];
  float* out = (float*)d_out;
  float* ws  = (float*)d_ws;

  kT<<<2560, 256, 0, stream>>>(ipw, W, Bm, orw, oiw, ws);
  kA<<<256, 256, 0, stream>>>(xr, xi, ws);
  kB<<<256, 256, 0, stream>>>(t, bias, ws);
  kC<<<256, 256, 0, stream>>>(out, ws);
}